// Round 1
// baseline (425.359 us; speedup 1.0000x reference)
//
#include <hip/hip_runtime.h>
#include <cstdint>

// Problem constants (match reference)
constexpr int N_TOK = 32768;
constexpr int DIM   = 1024;
constexpr int NEXP  = 64;
constexpr float CAPACITY = 40960.0f;   // int(1.25 * 32768)
constexpr float EPS_DEN  = 1e-6f;

// Persistent device scratch (avoids ws_size assumptions).
// g_sums: [0..63]=denom, [64..127]=importance, [128..191]=load, [192..255]=scale
__device__ float  g_sums[256];
__device__ float4 g_rec[N_TOK];   // per-row: {raw1, raw2, idx1, idx2}

__global__ void init_sums() {
    if (threadIdx.x < 192) g_sums[threadIdx.x] = 0.0f;
}

// ---------------------------------------------------------------------------
// Kernel 1: fused GEMM (x @ w^T + b) + softmax + top-2 + per-expert sums
//   lane == expert (wave64 == 64 experts)
//   block = 256 threads (4 waves), each wave owns RPW=8 rows -> 32 rows/block
// ---------------------------------------------------------------------------
#define WAVES 4
#define RPW   8
#define ROWS_PER_BLK (WAVES * RPW)   // 32
#define BK    64                     // K-tile (floats)

__global__ __launch_bounds__(256, 4)
void gate_main(const float* __restrict__ x,
               const float* __restrict__ wg,
               const float* __restrict__ bg) {
    // w tile transposed: wt[k4][e] (column e XOR-swizzled by k4&7 -> conflict-free b128)
    __shared__ float4 wt[BK / 4][NEXP];          // 16 KB
    __shared__ float4 xs[WAVES][RPW][BK / 4];    // 8 KB

    const int tid  = threadIdx.x;
    const int lane = tid & 63;
    const int wv   = tid >> 6;
    const int row0 = blockIdx.x * ROWS_PER_BLK + wv * RPW;

    float acc[RPW];
#pragma unroll
    for (int r = 0; r < RPW; ++r) acc[r] = 0.0f;

    const float4* x4 = (const float4*)x;
    const float4* w4 = (const float4*)wg;

    for (int kt = 0; kt < DIM / BK; ++kt) {
        __syncthreads();
        // stage w tile (transposed + swizzled): 16x64 float4
#pragma unroll
        for (int i = 0; i < 4; ++i) {
            int j  = tid + 256 * i;          // 0..1023
            int k4 = j & 15;
            int e  = j >> 4;
            float4 val = w4[(size_t)e * (DIM / 4) + kt * (BK / 4) + k4];
            wt[k4][e ^ (k4 & 7)] = val;
        }
        // stage this wave's 8 rows x 64 floats of x (coalesced), linear layout
#pragma unroll
        for (int i = 0; i < 2; ++i) {
            int m  = lane + 64 * i;          // 0..127
            int r  = m >> 4;
            int c4 = m & 15;
            xs[wv][r][c4] = x4[(size_t)(row0 + r) * (DIM / 4) + kt * (BK / 4) + c4];
        }
        __syncthreads();

#pragma unroll
        for (int k4 = 0; k4 < BK / 4; ++k4) {
            float4 wvv = wt[k4][lane ^ (k4 & 7)];
#pragma unroll
            for (int r = 0; r < RPW; ++r) {
                float4 xv = xs[wv][r][k4];   // broadcast read (same addr all lanes)
                acc[r] = fmaf(xv.x, wvv.x, acc[r]);
                acc[r] = fmaf(xv.y, wvv.y, acc[r]);
                acc[r] = fmaf(xv.z, wvv.z, acc[r]);
                acc[r] = fmaf(xv.w, wvv.w, acc[r]);
            }
        }
    }

    // ---- epilogue: softmax + top-2 per row, local per-expert accumulation ----
    const float b = bg[lane];
    float den_acc = 0.0f, imp_acc = 0.0f, load_acc = 0.0f;

    for (int r = 0; r < RPW; ++r) {
        float v = acc[r] + b;

        float m = v;
#pragma unroll
        for (int off = 32; off; off >>= 1) m = fmaxf(m, __shfl_xor(m, off));

        float ev = expf(v - m);
        float s = ev;
#pragma unroll
        for (int off = 32; off; off >>= 1) s += __shfl_xor(s, off);

        float raw = ev / s;   // softmax score for expert `lane`

        // top-1: lowest lane index attaining the max (matches jax top_k ties)
        unsigned long long mk1 = __ballot(v == m);
        int idx1 = __ffsll(mk1) - 1;

        float v2 = (lane == idx1) ? -INFINITY : v;
        float m2 = v2;
#pragma unroll
        for (int off = 32; off; off >>= 1) m2 = fmaxf(m2, __shfl_xor(m2, off));
        unsigned long long mk2 = __ballot(v2 == m2);
        int idx2 = __ffsll(mk2) - 1;

        bool sel = (lane == idx1) || (lane == idx2);
        imp_acc += raw;
        if (sel) { den_acc += raw; load_acc += 1.0f; }

        float raw1 = __shfl(raw, idx1);
        float raw2 = __shfl(raw, idx2);
        if (lane == 0) {
            g_rec[row0 + r] = make_float4(raw1, raw2,
                                          __int_as_float(idx1), __int_as_float(idx2));
        }
    }

    // device-scope atomics; 64 consecutive floats per array -> low contention
    atomicAdd(&g_sums[lane],       den_acc);
    atomicAdd(&g_sums[64 + lane],  imp_acc);
    atomicAdd(&g_sums[128 + lane], load_acc);
}

// ---------------------------------------------------------------------------
// Kernel 2: finalize — scale[e] = capacity / (denom[e] + eps); aux loss scalar
// ---------------------------------------------------------------------------
__global__ void finalize(float* __restrict__ out) {
    int e = threadIdx.x;    // 64 threads
    float den  = g_sums[e];
    float imp  = g_sums[64 + e];
    float load = g_sums[128 + e];
    g_sums[192 + e] = CAPACITY / (den + EPS_DEN);

    float prod = imp * load;
#pragma unroll
    for (int off = 32; off; off >>= 1) prod += __shfl_xor(prod, off);

    if (e == 0) {
        // aux = 0.01 * mean_e(imp_sum*load_sum / N^2) * 64^2 = 0.64 * sum / N^2
        float S = prod / ((float)N_TOK * (float)N_TOK);
        out[(size_t)N_TOK * NEXP] = 0.64f * S;
    }
}

// ---------------------------------------------------------------------------
// Kernel 3: scatter gate_scores — mostly zeros, 2 nonzero per row, coalesced
//   16 threads per row, each writes one float4 (row = 64 floats)
// ---------------------------------------------------------------------------
__global__ __launch_bounds__(256)
void scatter_out(float* __restrict__ out) {
    __shared__ float scale_s[NEXP];
    int tid = threadIdx.x;
    if (tid < NEXP) scale_s[tid] = g_sums[192 + tid];
    __syncthreads();

    int row = blockIdx.x * 16 + (tid >> 4);
    int g   = tid & 15;

    float4 rec = g_rec[row];
    int i1 = __float_as_int(rec.z);
    int i2 = __float_as_int(rec.w);
    float s1 = rec.x * scale_s[i1];
    float s2 = rec.y * scale_s[i2];

    int base = g * 4;
    float4 o;
    o.x = (i1 == base + 0) ? s1 : ((i2 == base + 0) ? s2 : 0.0f);
    o.y = (i1 == base + 1) ? s1 : ((i2 == base + 1) ? s2 : 0.0f);
    o.z = (i1 == base + 2) ? s1 : ((i2 == base + 2) ? s2 : 0.0f);
    o.w = (i1 == base + 3) ? s1 : ((i2 == base + 3) ? s2 : 0.0f);

    ((float4*)out)[(size_t)row * 16 + g] = o;
}

// ---------------------------------------------------------------------------
extern "C" void kernel_launch(void* const* d_in, const int* in_sizes, int n_in,
                              void* d_out, int out_size, void* d_ws, size_t ws_size,
                              hipStream_t stream) {
    const float* x  = (const float*)d_in[0];
    const float* wg = (const float*)d_in[1];
    const float* bg = (const float*)d_in[2];
    float* out = (float*)d_out;

    hipLaunchKernelGGL(init_sums, dim3(1), dim3(256), 0, stream);
    hipLaunchKernelGGL(gate_main, dim3(N_TOK / ROWS_PER_BLK), dim3(256), 0, stream,
                       x, wg, bg);
    hipLaunchKernelGGL(finalize, dim3(1), dim3(64), 0, stream, out);
    hipLaunchKernelGGL(scatter_out, dim3(N_TOK / 16), dim3(256), 0, stream, out);
}